// Round 12
// baseline (98.251 us; speedup 1.0000x reference)
//
#include <hip/hip_runtime.h>
#include <math.h>

#define F 128
#define HEADS 4
#define DHEAD 32
#define HIST_H 128         // segments per class; 8*HIST_H hist/scatter blocks
#define CW_MAX 6592        // max nodes per class (LDS cap); N <= 52736

typedef unsigned short ushort_t;
typedef __attribute__((ext_vector_type(8))) short short8;   // 8 bf16 (4 VGPR)
typedef __attribute__((ext_vector_type(4))) float f32x4;    // MFMA acc

// round-to-nearest-even fp32 -> bf16
__device__ __forceinline__ ushort_t f2bf(float x) {
  unsigned u = __float_as_uint(x);
  unsigned r = u + 0x7FFFu + ((u >> 16) & 1u);
  return (ushort_t)(r >> 16);
}

// unpack 8 packed bf16 (as int4) -> 8 fp32
__device__ __forceinline__ void unpack8(const int4& r, float* v) {
  int rr[4] = {r.x, r.y, r.z, r.w};
#pragma unroll
  for (int q = 0; q < 4; q++) {
    unsigned u = (unsigned)rr[q];
    v[2 * q] = __uint_as_float(u << 16);
    v[2 * q + 1] = __uint_as_float(u & 0xFFFF0000u);
  }
}

// ---------------------------------------------------------------------------
// K-1: pack W (128x128 fp32) into MFMA-fragment-ordered bf16 hi/lo arrays.
// ---------------------------------------------------------------------------
__global__ __launch_bounds__(256) void wprep_kernel(
    const float* __restrict__ W, ushort_t* __restrict__ whi,
    ushort_t* __restrict__ wlo) {
  int idx = blockIdx.x * 256 + threadIdx.x;  // 0..16383
  if (idx >= 128 * 128) return;
  int j = idx & 7;
  int lane = (idx >> 3) & 63;
  int f = idx >> 9;  // kt*8+nt
  int kt = f >> 3, nt = f & 7;
  int k = kt * 32 + (lane >> 4) * 8 + j;
  int n = nt * 16 + (lane & 15);
  float w = W[k * 128 + n];
  unsigned u = __float_as_uint(w);
  unsigned hb = u & 0xFFFF0000u;
  float lo = w - __uint_as_float(hb);
  whi[idx] = (ushort_t)(hb >> 16);
  wlo[idx] = f2bf(lo);
}

// ---------------------------------------------------------------------------
// K1: fused  [0..gemmBlocks): ft = feat @ W via split-precision bf16 MFMA
//            [gemmBlocks..+8*HIST_H): LDS partial histograms -> u16 partials.
// ---------------------------------------------------------------------------
__global__ __launch_bounds__(256) void gemm_hist_kernel(
    const float* __restrict__ feat, const ushort_t* __restrict__ whi,
    const ushort_t* __restrict__ wlo, ushort_t* __restrict__ ftb, int N,
    const int* __restrict__ dst, ushort_t* __restrict__ partials, int cwp,
    int E, int gemmBlocks) {
  __shared__ int lh[CW_MAX];
  if ((int)blockIdx.x >= gemmBlocks) {
    // ---- partial histogram path (LDS atomics only) ----
    const int hb = blockIdx.x - gemmBlocks;
    const int cls = hb & 7;
    const int h = hb >> 3;
    const int cw = (N + 7) >> 3;
    const int nbase = cls * cw;
    for (int j = threadIdx.x; j < cw; j += 256) lh[j] = 0;
    __syncthreads();
    const int seg = (E + HIST_H - 1) / HIST_H;
    const int e0 = h * seg;
    const int e1 = min(e0 + seg, E);
    int e = e0 + (int)threadIdx.x;
    for (; e + 768 < e1; e += 1024) {
      int d0 = dst[e];
      int d1 = dst[e + 256];
      int d2 = dst[e + 512];
      int d3 = dst[e + 768];
      if ((unsigned)(d0 - nbase) < (unsigned)cw) atomicAdd(&lh[d0 - nbase], 1);
      if ((unsigned)(d1 - nbase) < (unsigned)cw) atomicAdd(&lh[d1 - nbase], 1);
      if ((unsigned)(d2 - nbase) < (unsigned)cw) atomicAdd(&lh[d2 - nbase], 1);
      if ((unsigned)(d3 - nbase) < (unsigned)cw) atomicAdd(&lh[d3 - nbase], 1);
    }
    for (; e < e1; e += 256) {
      int d = dst[e];
      if ((unsigned)(d - nbase) < (unsigned)cw) atomicAdd(&lh[d - nbase], 1);
    }
    __syncthreads();
    ushort_t* prow = partials + (size_t)(cls * HIST_H + h) * cwp;
    for (int j = threadIdx.x; j < cw; j += 256) prow[j] = (ushort_t)lh[j];
    return;
  }
  // ---- MFMA GEMM path ----
  const int t = threadIdx.x;
  const int wv = t >> 6;  // wave 0..3
  const int l = t & 63;
  const int g = l >> 4;   // lane group 0..3
  const int lm = l & 15;
  const int arow = blockIdx.x * 64 + wv * 16 + lm;
  const int arowc = min(arow, N - 1);  // clamp OOB loads (rows independent)

  f32x4 acc[8];
#pragma unroll
  for (int nt = 0; nt < 8; nt++) acc[nt] = (f32x4){0.f, 0.f, 0.f, 0.f};

#pragma unroll
  for (int kt = 0; kt < 4; kt++) {
    const float* ap = feat + (size_t)arowc * F + kt * 32 + g * 8;
    float a[8];
    *(float4*)&a[0] = *(const float4*)ap;
    *(float4*)&a[4] = *(const float4*)(ap + 4);
    short8 ahi, alo;
#pragma unroll
    for (int j = 0; j < 8; j++) {
      unsigned u = __float_as_uint(a[j]);
      unsigned hb2 = u & 0xFFFF0000u;
      float lo = a[j] - __uint_as_float(hb2);
      ahi[j] = (short)(hb2 >> 16);
      alo[j] = (short)f2bf(lo);
    }
    const ushort_t* bh = whi + (size_t)(kt * 8) * 512 + l * 8;  // frag=512 sh
    const ushort_t* bl = wlo + (size_t)(kt * 8) * 512 + l * 8;
#pragma unroll
    for (int nt = 0; nt < 8; nt++) {
      short8 bhi = *(const short8*)(bh + nt * 512);
      short8 blo = *(const short8*)(bl + nt * 512);
      acc[nt] =
          __builtin_amdgcn_mfma_f32_16x16x32_bf16(ahi, blo, acc[nt], 0, 0, 0);
      acc[nt] =
          __builtin_amdgcn_mfma_f32_16x16x32_bf16(alo, bhi, acc[nt], 0, 0, 0);
      acc[nt] =
          __builtin_amdgcn_mfma_f32_16x16x32_bf16(ahi, bhi, acc[nt], 0, 0, 0);
    }
  }

  // epilogue: C/D layout col = lane&15, row = (lane>>4)*4 + reg (m89-verified)
  const int orow0 = blockIdx.x * 64 + wv * 16 + g * 4;
#pragma unroll
  for (int reg = 0; reg < 4; reg++) {
    int orow = orow0 + reg;
    if (orow < N) {
#pragma unroll
      for (int nt = 0; nt < 8; nt++)
        ftb[(size_t)orow * F + nt * 16 + lm] = f2bf(acc[nt][reg]);
    }
  }
}

// ---------------------------------------------------------------------------
// K3a: single pass over partials: emits rel16 (relative segment cursors) and
// node totals -> block-local exclusive prefix into offs + per-block sums.
// ---------------------------------------------------------------------------
__global__ void scan_block_kernel(const ushort_t* __restrict__ partials,
                                  int cwp, int* __restrict__ offs,
                                  ushort_t* __restrict__ rel16,
                                  int* __restrict__ bsums, int N) {
  __shared__ int s[256];
  int t = threadIdx.x, i = blockIdx.x * 256 + t;
  int v = 0;
  if (i < N) {
    int cw = (N + 7) >> 3;
    int c = i / cw;
    int j = i - c * cw;
    const ushort_t* pb = partials + (size_t)c * HIST_H * cwp + j;
    ushort_t* cb = rel16 + (size_t)c * HIST_H * cwp + j;
    int run = 0;
#pragma unroll 8
    for (int h = 0; h < HIST_H; h++) {
      cb[(size_t)h * cwp] = (ushort_t)run;
      run += pb[(size_t)h * cwp];
    }
    v = run;  // node total degree
  }
  s[t] = v;
  __syncthreads();
  for (int d = 1; d < 256; d <<= 1) {
    int x = (t >= d) ? s[t - d] : 0;
    __syncthreads();
    s[t] += x;
    __syncthreads();
  }
  if (i < N) offs[i] = s[t] - v;  // block-local exclusive
  if (t == 255) bsums[blockIdx.x] = s[255];
}

// K3b: finish offs with block-sum prefix; write sentinel offs[N] = E.
__global__ void scan_finish_kernel(int* __restrict__ offs,
                                   const int* __restrict__ bsums, int N,
                                   int E) {
  int t = threadIdx.x, b = blockIdx.x;
  int v = (t < b) ? bsums[t] : 0;  // nb <= 256 guaranteed
#pragma unroll
  for (int d = 32; d > 0; d >>= 1) v += __shfl_down(v, d, 64);
  __shared__ int wsum[4];
  if ((t & 63) == 0) wsum[t >> 6] = v;
  __syncthreads();
  int total = wsum[0] + wsum[1] + wsum[2] + wsum[3];
  int i = b * 256 + t;
  if (i < N) offs[i] += total;
  if (b == 0 && t == 0) offs[N] = E;  // sentinel
}

// ---------------------------------------------------------------------------
// K4: scatter, zero global atomics. Block (cls,h): lcur[j] = offs[nbase+j]
// + rel16 row; rescans segment h (4-deep batched), LDS-atomicAdd -> exact
// csr slot. csr lines of a class owned by one XCD (bid&7) -> L2 merge.
// ---------------------------------------------------------------------------
__global__ __launch_bounds__(256) void scatter_kernel(
    const int* __restrict__ src, const int* __restrict__ dst,
    const int* __restrict__ offs, const ushort_t* __restrict__ rel16, int cwp,
    int* __restrict__ csr, int E, int N) {
  __shared__ int lcur[CW_MAX];
  const int cls = blockIdx.x & 7;
  const int h = blockIdx.x >> 3;
  const int cw = (N + 7) >> 3;
  const int nbase = cls * cw;
  const int jmax = min(cw, N - nbase);
  const ushort_t* crow = rel16 + (size_t)(cls * HIST_H + h) * cwp;
  for (int j = threadIdx.x; j < jmax; j += 256)
    lcur[j] = offs[nbase + j] + (int)crow[j];
  __syncthreads();
  const int seg = (E + HIST_H - 1) / HIST_H;
  const int e0 = h * seg;
  const int e1 = min(e0 + seg, E);
  int e = e0 + (int)threadIdx.x;
  for (; e + 768 < e1; e += 1024) {
    int d0 = dst[e];
    int d1 = dst[e + 256];
    int d2 = dst[e + 512];
    int d3 = dst[e + 768];
    int s0 = src[e];
    int s1 = src[e + 256];
    int s2 = src[e + 512];
    int s3 = src[e + 768];
    if ((unsigned)(d0 - nbase) < (unsigned)cw)
      csr[atomicAdd(&lcur[d0 - nbase], 1)] = s0;
    if ((unsigned)(d1 - nbase) < (unsigned)cw)
      csr[atomicAdd(&lcur[d1 - nbase], 1)] = s1;
    if ((unsigned)(d2 - nbase) < (unsigned)cw)
      csr[atomicAdd(&lcur[d2 - nbase], 1)] = s2;
    if ((unsigned)(d3 - nbase) < (unsigned)cw)
      csr[atomicAdd(&lcur[d3 - nbase], 1)] = s3;
  }
  for (; e < e1; e += 256) {
    int d = dst[e];
    int sv = src[e];
    if ((unsigned)(d - nbase) < (unsigned)cw)
      csr[atomicAdd(&lcur[d - nbase], 1)] = sv;
  }
}

// ---------------------------------------------------------------------------
// K5: fused per-node online-softmax aggregation, bf16 ft.
// ONE WAVE PER NODE: 4 edge-groups of 16 lanes (group g takes edges g, g+4,
// g+8, ... with its own online-softmax state, 4-deep pipelined -> 16 gathers
// in flight per wave). Cross-group merge at the end via exp2-rescaled
// shfl_xor(16/32) tree. Within a group: lane = h*4+sub, 8 dims/lane.
// ---------------------------------------------------------------------------
__global__ __launch_bounds__(256) void aggregate_kernel(
    const ushort_t* __restrict__ ftb, const int* __restrict__ offs,
    const int* __restrict__ csr, const float* __restrict__ bias,
    float* __restrict__ out, int N) {
  const int T = blockIdx.x * 256 + threadIdx.x;
  const int n = T >> 6;  // one wave per node
  if (n >= N) return;
  const int l = T & 63;
  const int g = l >> 4;        // edge group 0..3
  const int h = (l >> 2) & 3;  // head
  const int sub = l & 3;       // quarter of a head's D
  const int dimBase = h * DHEAD + sub * 8;

  const int off = offs[n];
  const int deg = offs[n + 1] - off;

  float4 b0 = *(const float4*)&bias[dimBase];
  float4 b1 = *(const float4*)&bias[dimBase + 4];

  if (deg == 0) {  // out = bias
    if (g == 0) {
      f32x4 o0 = {b0.x, b0.y, b0.z, b0.w};
      f32x4 o1 = {b1.x, b1.y, b1.z, b1.w};
      __builtin_nontemporal_store(o0, (f32x4*)&out[n * F + dimBase]);
      __builtin_nontemporal_store(o1, (f32x4*)&out[n * F + dimBase + 4]);
    }
    return;
  }

  float ftd[8];
  {
    int4 r = *(const int4*)&ftb[n * F + dimBase];
    unpack8(r, ftd);
  }

  const float LOG2E = 1.4426950408889634f;
  float m = -INFINITY, s = 0.f;
  float acc[8];
#pragma unroll
  for (int j = 0; j < 8; j++) acc[j] = 0.f;

#define PROCESS(RX)                                              \
  do {                                                           \
    float v[8];                                                  \
    unpack8(RX, v);                                              \
    float part = 0.f;                                            \
    _Pragma("unroll") for (int j = 0; j < 8; j++) part =         \
        fmaf(ftd[j], v[j], part);                                \
    part += __shfl_xor(part, 1, 4);                              \
    part += __shfl_xor(part, 2, 4);                              \
    float el = part * LOG2E;                                     \
    float mn = fmaxf(m, el);                                     \
    float scale = exp2f(m - mn);                                 \
    float w = exp2f(el - mn);                                    \
    s = fmaf(s, scale, w);                                       \
    _Pragma("unroll") for (int j = 0; j < 8; j++) acc[j] =       \
        fmaf(acc[j], scale, w * v[j]);                           \
    m = mn;                                                      \
  } while (0)

  // group g handles edges g, g+4, g+8, ... (K of them), 4-deep pipelined
  const int K = (deg > g) ? ((deg - g + 3) >> 2) : 0;
  const int dm1 = deg - 1;
  int4 R0 = make_int4(0, 0, 0, 0), R1 = R0, R2 = R0, R3 = R0;
  if (K > 0) {
    int s0 = csr[off + g];
    int s1 = csr[off + min(g + 4, dm1)];
    int s2 = csr[off + min(g + 8, dm1)];
    int s3 = csr[off + min(g + 12, dm1)];
    R0 = *(const int4*)&ftb[s0 * F + dimBase];
    R1 = *(const int4*)&ftb[s1 * F + dimBase];
    R2 = *(const int4*)&ftb[s2 * F + dimBase];
    R3 = *(const int4*)&ftb[s3 * F + dimBase];
  }
  int k = 0;
  for (; k + 4 <= K; k += 4) {
    // clamped prefetch of the next 4 group-edges
    int sa = csr[off + min(g + 4 * (k + 4), dm1)];
    int sb = csr[off + min(g + 4 * (k + 5), dm1)];
    int sc = csr[off + min(g + 4 * (k + 6), dm1)];
    int sd = csr[off + min(g + 4 * (k + 7), dm1)];
    int4 Na = *(const int4*)&ftb[sa * F + dimBase];
    int4 Nb = *(const int4*)&ftb[sb * F + dimBase];
    int4 Nc = *(const int4*)&ftb[sc * F + dimBase];
    int4 Nd = *(const int4*)&ftb[sd * F + dimBase];
    PROCESS(R0);
    PROCESS(R1);
    PROCESS(R2);
    PROCESS(R3);
    R0 = Na; R1 = Nb; R2 = Nc; R3 = Nd;
  }
  int r = K - k;  // 0..3 remaining, already resident in R0..R2
  if (r > 0) PROCESS(R0);
  if (r > 1) PROCESS(R1);
  if (r > 2) PROCESS(R2);
#undef PROCESS

  // ---- cross-group merge (lane bits 4,5). Empty group: m=-inf -> w=0. ----
  float mo = fmaxf(m, __shfl_xor(m, 16));
  mo = fmaxf(mo, __shfl_xor(mo, 32));  // deg>0 => mo finite
  float wg = exp2f(m - mo);
  s *= wg;
  s += __shfl_xor(s, 16);
  s += __shfl_xor(s, 32);
#pragma unroll
  for (int j = 0; j < 8; j++) {
    acc[j] *= wg;
    acc[j] += __shfl_xor(acc[j], 16);
    acc[j] += __shfl_xor(acc[j], 32);
  }

  if (g == 0) {
    float inv = 1.f / s;
    f32x4 o0 = {acc[0] * inv + b0.x, acc[1] * inv + b0.y, acc[2] * inv + b0.z,
                acc[3] * inv + b0.w};
    f32x4 o1 = {acc[4] * inv + b1.x, acc[5] * inv + b1.y, acc[6] * inv + b1.z,
                acc[7] * inv + b1.w};
    // out has no reuse: nontemporal stores keep L2 for the ftb gather
    __builtin_nontemporal_store(o0, (f32x4*)&out[n * F + dimBase]);
    __builtin_nontemporal_store(o1, (f32x4*)&out[n * F + dimBase + 4]);
  }
}

// ---------------------------------------------------------------------------
extern "C" void kernel_launch(void* const* d_in, const int* in_sizes, int n_in,
                              void* d_out, int out_size, void* d_ws,
                              size_t ws_size, hipStream_t stream) {
  const float* feat = (const float*)d_in[0];
  const int* src = (const int*)d_in[1];
  const int* dst = (const int*)d_in[2];
  const float* W = (const float*)d_in[3];
  const float* bias = (const float*)d_in[4];
  float* out = (float*)d_out;

  const int N = in_sizes[0] / F;
  const int E = in_sizes[1];
  const int cw = (N + 7) >> 3;      // nodes per class (<= CW_MAX)
  const int cwp = (cw + 31) & ~31;  // padded u16 row (64B aligned)

  // workspace layout (~43 MB used)
  char* ws = (char*)d_ws;
  ushort_t* ftb = (ushort_t*)ws;  // N*128 bf16 = 12.8 MB
  size_t ftB = (size_t)N * F * sizeof(ushort_t);
  ftB = (ftB + 255) & ~(size_t)255;
  int* offs = (int*)(ws + ftB);                   // N+1
  int* bsums = offs + N + 1;                      // 256
  int* csr = bsums + 256;                         // E
  ushort_t* whi = (ushort_t*)(csr + E);           // 16384 shorts (32 KB)
  ushort_t* wlo = whi + 128 * 128;                // 16384 shorts (32 KB)
  ushort_t* partials = wlo + 128 * 128;           // 8*HIST_H*cwp u16 (12.9MB)
  ushort_t* rel16 = partials + 8 * HIST_H * cwp;  // 8*HIST_H*cwp u16 (12.9MB)

  wprep_kernel<<<64, 256, 0, stream>>>(W, whi, wlo);

  int gemmBlocks = (N + 63) / 64;
  gemm_hist_kernel<<<gemmBlocks + 8 * HIST_H, 256, 0, stream>>>(
      feat, whi, wlo, ftb, N, dst, partials, cwp, E, gemmBlocks);

  int nb = (N + 255) / 256;  // 196 for N=50000 (must be <= 256)
  scan_block_kernel<<<nb, 256, 0, stream>>>(partials, cwp, offs, rel16,
                                            bsums, N);
  scan_finish_kernel<<<nb, 256, 0, stream>>>(offs, bsums, N, E);

  scatter_kernel<<<8 * HIST_H, 256, 0, stream>>>(src, dst, offs, rel16, cwp,
                                                 csr, E, N);

  // one wave per node
  aggregate_kernel<<<(N + 3) / 4, 256, 0, stream>>>(ftb, offs, csr, bias, out,
                                                    N);
}